// Round 1
// baseline (457.116 us; speedup 1.0000x reference)
//
#include <hip/hip_runtime.h>
#include <cstdint>
#include <cstddef>

// Problem constants
#define T_STEPS 12
#define N_NODES 4096
#define F_INP   64
#define H_G     128
#define H_L     128
#define N_CLS   10
#define N_EDGES 65536
#define G4      (4 * H_L)        // 512 gate columns

// Parallel-segment scan (verified in prior session: W=48 err <= 1.6e-7,
// 10x under the 1.76e-6 budget). Segments with s*L < W clamp to node 0 (EXACT).
#define SEG_L   16
#define SEG_W   48
#define NSEG    (N_NODES / SEG_L)   // 256 parallel segments

// R17 (this session): single persistent mega-kernel. Theory: per-kernel device
// work sums to ~100-140us vs 313us measured -> the residual is ~13 serial
// dispatch boundaries + whole-GPU-idle stages. Fuse everything into ONE
// 256-block x 512-thread kernel with a hand-rolled agent-scope grid barrier.
// Co-residency is guaranteed: grid == 256 == #CUs, launch_bounds(512,2) caps
// VGPR<=256, LDS 8.7KB -> 1 block/CU always fits -> no deadlock.
// Block-diagonal fusion: agg for nodes [16b,16b+16) feeds exactly gemm rows
// [16b,16b+16) of the same block -> agg output stays in LDS (no global
// round-trip, no barrier). rec1's kept h rows stay in LDS and feed gemm_p2
// directly (H1 global buffer eliminated). 13 sync points -> 8 grid barriers.

#define NBLK    256
#define NTHR    512
#define TOTAL_THR (NBLK * NTHR)     // 131072

typedef _Float16 half_t;
typedef half_t v8h __attribute__((ext_vector_type(8)));
typedef float v4f __attribute__((ext_vector_type(4)));

// Raw barrier: LDS-only drain (prior-session win). __syncthreads() would drain
// vmcnt(0) every step, stalling the in-flight P prefetch.
#define BARRIER_LDS() asm volatile("s_waitcnt lgkmcnt(0)\n\ts_barrier" ::: "memory")

// Keepalive pin: forces fragment liveness; harmless either way.
#define PIN_V(x) asm volatile("" : "+v"(x))

// fast sigmoid/tanh: v_exp_f32 + v_rcp_f32 only
__device__ __forceinline__ float fsigmoid_(float x) {
    float e = __builtin_amdgcn_exp2f(-1.44269504f * x);
    return __builtin_amdgcn_rcpf(1.0f + e);
}
__device__ __forceinline__ float ftanh_(float x) {
    float e = __builtin_amdgcn_exp2f(2.88539008f * x);
    return 1.0f - 2.0f * __builtin_amdgcn_rcpf(e + 1.0f);
}
__device__ __forceinline__ float geluf_(float x) { return 0.5f * x * (1.0f + erff(x * 0.70710678f)); }

// gate-column permutation: col' = 4*hu + gate  ->  natural col = gate*128 + hu
__device__ __forceinline__ int orig_col_(int cp) { return (cp & 3) * 128 + (cp >> 2); }

// ---------------- grid barrier (agent scope, phase-counting) ----------------
// bar is memset to 0 before each launch (captured in the graph). Each barrier k
// waits until the counter reaches 256*(k+1). Release: __threadfence (L2 wb at
// agent scope) + RELEASE add. Acquire: ACQUIRE spin load (L2 inv). Other waves
// of the block are held at the trailing __syncthreads. Bounded spin converts
// any co-residency surprise into a wrong answer instead of a hang.
__device__ __forceinline__ void gsync(unsigned* bar, unsigned target) {
    __syncthreads();   // drains vmcnt/lgkmcnt per wave, block-local order
    if (threadIdx.x == 0) {
        __threadfence();
        __hip_atomic_fetch_add(bar, 1u, __ATOMIC_RELEASE, __HIP_MEMORY_SCOPE_AGENT);
        int guard = 0;
        while (__hip_atomic_load(bar, __ATOMIC_ACQUIRE, __HIP_MEMORY_SCOPE_AGENT) < target) {
            __builtin_amdgcn_s_sleep(2);
            if (++guard > (1 << 20)) break;   // safety: fail visibly, never hang
        }
    }
    __syncthreads();
}

// ---------------- kernel argument block ----------------
struct MegaArgs {
    const float* x11;
    const int* erow;
    const int* ecol;
    const float* ew;
    const float *W1, *b1, *W2, *b2, *W3, *b3;
    const float *Wih1, *Wih2, *Whh1, *Whh2;
    const float *bih1, *bhh1, *bih2, *bhh2;
    const float *Wfc, *bfc;
    float* out;
    float* deg;
    int* cnt;
    float* dinv;
    int* row_ptr;
    int* csr_src;
    float* csr_w;
    float* WT;          // WihT1_perm | WihT2_perm (2 x 65536 floats)
    half_t* WhhF;       // f16 fragment weights, both layers (2 x 65536 halfs)
    float* h_buf;       // GCN ping
    float* hw_buf;      // GCN pong
    float* P1;
    float* P2;
    unsigned* bar;
};

// ---------------- stage device functions (all force-inlined) ----------------

// exclusive scan of cnt[4096] -> row_ptr + cursor(cnt); block 0 only, 512 thr
__device__ __forceinline__ void scan512(int* cnt, int* row_ptr, int* s) {
    int tid = threadIdx.x;
    int4 va = ((const int4*)cnt)[tid * 2];
    int4 vb = ((const int4*)cnt)[tid * 2 + 1];
    int local = va.x + va.y + va.z + va.w + vb.x + vb.y + vb.z + vb.w;
    s[tid] = local;
    __syncthreads();
    for (int off = 1; off < 512; off <<= 1) {
        int v = (tid >= off) ? s[tid - off] : 0;
        __syncthreads();
        s[tid] += v;
        __syncthreads();
    }
    int base = s[tid] - local;
    int4 oa, ob;
    oa.x = base;
    oa.y = oa.x + va.x;
    oa.z = oa.y + va.y;
    oa.w = oa.z + va.z;
    ob.x = oa.w + va.w;
    ob.y = ob.x + vb.x;
    ob.z = ob.y + vb.y;
    ob.w = ob.z + vb.z;
    ((int4*)row_ptr)[tid * 2] = oa;
    ((int4*)row_ptr)[tid * 2 + 1] = ob;
    ((int4*)cnt)[tid * 2] = oa;          // cursor for scatter
    ((int4*)cnt)[tid * 2 + 1] = ob;
    if (tid == 511) row_ptr[4096] = ob.w + vb.w;
}

// C[16,128] = A[16rows from global, K] @ B[K,128], K=64 (GCN layer 1)
__device__ __forceinline__ void gemm_g64(const float* __restrict__ A,
                                         const float* __restrict__ B,
                                         float* __restrict__ C, int blk, float* sA) {
    constexpr int K = F_INP, KP = K + 4;
    int tid = threadIdx.x;
    size_t m0 = (size_t)blk * 16;
    for (int task = tid; task < 16 * (K / 4); task += NTHR) {
        int rr = task >> 4, kc = task & 15;
        *(float4*)&sA[rr * KP + kc * 4] = *(const float4*)(A + (m0 + rr) * K + kc * 4);
    }
    __syncthreads();
    int tn = tid & 31;
    int tm = tid >> 5;   // 16 rows, 1 row/thread
    float a0 = 0.f, a1 = 0.f, a2 = 0.f, a3 = 0.f;
    for (int k = 0; k < K; k += 4) {
        float4 b0 = *(const float4*)(B + (size_t)(k + 0) * H_G + tn * 4);
        float4 b1 = *(const float4*)(B + (size_t)(k + 1) * H_G + tn * 4);
        float4 b2 = *(const float4*)(B + (size_t)(k + 2) * H_G + tn * 4);
        float4 b3 = *(const float4*)(B + (size_t)(k + 3) * H_G + tn * 4);
        float4 aa = *(const float4*)&sA[tm * KP + k];
        a0 += aa.x * b0.x + aa.y * b1.x + aa.z * b2.x + aa.w * b3.x;
        a1 += aa.x * b0.y + aa.y * b1.y + aa.z * b2.y + aa.w * b3.y;
        a2 += aa.x * b0.z + aa.y * b1.z + aa.z * b2.z + aa.w * b3.z;
        a3 += aa.x * b0.w + aa.y * b1.w + aa.z * b2.w + aa.w * b3.w;
    }
    *(float4*)(C + (m0 + tm) * H_G + tn * 4) = make_float4(a0, a1, a2, a3);
}

// CSR aggregation + bias + exact GELU for this block's 16 nodes -> LDS sA[16][128]
__device__ __forceinline__ void agg_lds(const float* __restrict__ hw,
                                        const int* __restrict__ row_ptr,
                                        const int* __restrict__ csr_src,
                                        const float* __restrict__ csr_w,
                                        const float* __restrict__ bias,
                                        float* sA, int blk) {
    int tid = threadIdx.x;
    int f4 = tid & 31;
    int nsub = tid >> 5;            // 16 nodes/block
    int n = blk * 16 + nsub;
    float4 acc = make_float4(0.f, 0.f, 0.f, 0.f);
    int e0 = row_ptr[n], e1 = row_ptr[n + 1];
    for (int e = e0; e < e1; e++) {
        int s = csr_src[e];
        float wv = csr_w[e];
        float4 v = *(const float4*)(hw + (size_t)s * H_G + f4 * 4);
        acc.x += wv * v.x;
        acc.y += wv * v.y;
        acc.z += wv * v.z;
        acc.w += wv * v.w;
    }
    float4 b = *(const float4*)(bias + f4 * 4);
    float4 o;
    o.x = geluf_(acc.x + b.x);
    o.y = geluf_(acc.y + b.y);
    o.z = geluf_(acc.z + b.z);
    o.w = geluf_(acc.w + b.w);
    *(float4*)&sA[nsub * 128 + f4 * 4] = o;
}

// C[16,128] = sA[16,128](LDS) @ B[128,128] (GCN layers 2/3)
__device__ __forceinline__ void gemm_lds128(const float* sA,
                                            const float* __restrict__ B,
                                            float* __restrict__ C, int blk) {
    int tid = threadIdx.x;
    size_t m0 = (size_t)blk * 16;
    int tn = tid & 31;
    int tm = tid >> 5;
    float a0 = 0.f, a1 = 0.f, a2 = 0.f, a3 = 0.f;
    for (int k = 0; k < H_G; k += 4) {
        float4 b0 = *(const float4*)(B + (size_t)(k + 0) * H_G + tn * 4);
        float4 b1 = *(const float4*)(B + (size_t)(k + 1) * H_G + tn * 4);
        float4 b2 = *(const float4*)(B + (size_t)(k + 2) * H_G + tn * 4);
        float4 b3 = *(const float4*)(B + (size_t)(k + 3) * H_G + tn * 4);
        float4 aa = *(const float4*)&sA[tm * 128 + k];
        a0 += aa.x * b0.x + aa.y * b1.x + aa.z * b2.x + aa.w * b3.x;
        a1 += aa.x * b0.y + aa.y * b1.y + aa.z * b2.y + aa.w * b3.y;
        a2 += aa.x * b0.z + aa.y * b1.z + aa.z * b2.z + aa.w * b3.z;
        a3 += aa.x * b0.w + aa.y * b1.w + aa.z * b2.w + aa.w * b3.w;
    }
    *(float4*)(C + (m0 + tm) * H_G + tn * 4) = make_float4(a0, a1, a2, a3);
}

// P[16 rows, 512] = Arows(LDS 16x128) @ BT[128,512] + permuted bias
__device__ __forceinline__ void gemmp_lds(const float* sArows,
                                          const float* __restrict__ BT,
                                          const float* __restrict__ bih,
                                          const float* __restrict__ bhh,
                                          float* __restrict__ Pout, int blk) {
    int tid = threadIdx.x;
    int r0 = blk * 16;
    int jc = tid & 127;
    int rg = tid >> 7;   // 4 groups x 4 rows
    float acc[4][4];
#pragma unroll
    for (int rr = 0; rr < 4; rr++)
#pragma unroll
        for (int j = 0; j < 4; j++) acc[rr][j] = 0.f;

    for (int k = 0; k < 128; k += 4) {
        float4 b0 = *(const float4*)(BT + (size_t)(k + 0) * G4 + jc * 4);
        float4 b1 = *(const float4*)(BT + (size_t)(k + 1) * G4 + jc * 4);
        float4 b2 = *(const float4*)(BT + (size_t)(k + 2) * G4 + jc * 4);
        float4 b3 = *(const float4*)(BT + (size_t)(k + 3) * G4 + jc * 4);
#pragma unroll
        for (int rr = 0; rr < 4; rr++) {
            float4 a = *(const float4*)&sArows[(rg * 4 + rr) * 128 + k];
            acc[rr][0] += a.x * b0.x + a.y * b1.x + a.z * b2.x + a.w * b3.x;
            acc[rr][1] += a.x * b0.y + a.y * b1.y + a.z * b2.y + a.w * b3.y;
            acc[rr][2] += a.x * b0.z + a.y * b1.z + a.z * b2.z + a.w * b3.z;
            acc[rr][3] += a.x * b0.w + a.y * b1.w + a.z * b2.w + a.w * b3.w;
        }
    }
    int c0 = jc * 4;
    float bx = bih[orig_col_(c0 + 0)] + bhh[orig_col_(c0 + 0)];
    float by = bih[orig_col_(c0 + 1)] + bhh[orig_col_(c0 + 1)];
    float bz = bih[orig_col_(c0 + 2)] + bhh[orig_col_(c0 + 2)];
    float bw = bih[orig_col_(c0 + 3)] + bhh[orig_col_(c0 + 3)];
#pragma unroll
    for (int rr = 0; rr < 4; rr++) {
        int lrow = r0 + rg * 4 + rr;
        *(float4*)(Pout + (size_t)lrow * G4 + jc * 4) =
            make_float4(acc[rr][0] + bx, acc[rr][1] + by, acc[rr][2] + bz, acc[rr][3] + bw);
    }
}

// MFMA LSTM recurrence for segment s; kept h rows land in LDS hkeep (smem+512)
__device__ __forceinline__ void rec_seg(const float* __restrict__ P,
                                        const half_t* __restrict__ WhhF,
                                        char* smem, int s) {
    half_t* sh = (half_t*)smem;              // [2][128] ping-pong h (f16)
    float* hkeep = (float*)(smem + 512);     // [16][128] kept h rows (f32)
    int write_start = s * SEG_L;
    int n_begin = write_start - SEG_W;
    if (n_begin < 0) n_begin = 0;
    int steps = write_start + SEG_L - n_begin;
    const float* Pp = P + (size_t)n_begin * G4;

    int tid = threadIdx.x;
    int lane = tid & 63;
    int w = tid >> 6;
    int m = lane & 15;
    int q = lane >> 4;
    int mm = m & 3;
    int hu = w * 16 + mm * 4 + q;

    const v8h* Af = (const v8h*)WhhF + (size_t)w * 16 * 64 + lane;
    v8h A[4][4];
#pragma unroll
    for (int mt = 0; mt < 4; mt++)
#pragma unroll
        for (int kt = 0; kt < 4; kt++)
            A[mt][kt] = Af[(mt * 4 + kt) * 64];
#pragma unroll
    for (int mt = 0; mt < 4; mt++)
#pragma unroll
        for (int kt = 0; kt < 4; kt++)
            PIN_V(A[mt][kt]);

    float c = 0.f;
    if (tid < H_L) sh[tid] = (half_t)0.f;

    v4f pn[2][4];
    const float* pb0 = Pp + w * 64 + q * 4;
#pragma unroll
    for (int s2 = 0; s2 < 2; s2++)
#pragma unroll
        for (int mt = 0; mt < 4; mt++)
            pn[s2][mt] = *(const v4f*)(pb0 + (size_t)s2 * G4 + mt * 16);
    __syncthreads();

    bool writer = (m < 4);

#pragma unroll 2
    for (int i = 0; i < steps; i++) {
        int par = i & 1;
        v4f acc0 = pn[par][0], acc1 = pn[par][1], acc2 = pn[par][2], acc3 = pn[par][3];
        int inx = (i + 2 < steps) ? (i + 2) : i;
        const float* pb = Pp + (size_t)inx * G4 + w * 64 + q * 4;
        pn[par][0] = *(const v4f*)(pb + 0);
        pn[par][1] = *(const v4f*)(pb + 16);
        pn[par][2] = *(const v4f*)(pb + 32);
        pn[par][3] = *(const v4f*)(pb + 48);

        const half_t* shc = sh + par * H_L;
        v8h B0 = *(const v8h*)(shc + q * 8);
        v8h B1 = *(const v8h*)(shc + 32 + q * 8);
        v8h B2 = *(const v8h*)(shc + 64 + q * 8);
        v8h B3 = *(const v8h*)(shc + 96 + q * 8);

        acc0 = __builtin_amdgcn_mfma_f32_16x16x32_f16(A[0][0], B0, acc0, 0, 0, 0);
        acc0 = __builtin_amdgcn_mfma_f32_16x16x32_f16(A[0][1], B1, acc0, 0, 0, 0);
        acc0 = __builtin_amdgcn_mfma_f32_16x16x32_f16(A[0][2], B2, acc0, 0, 0, 0);
        acc0 = __builtin_amdgcn_mfma_f32_16x16x32_f16(A[0][3], B3, acc0, 0, 0, 0);
        acc1 = __builtin_amdgcn_mfma_f32_16x16x32_f16(A[1][0], B0, acc1, 0, 0, 0);
        acc1 = __builtin_amdgcn_mfma_f32_16x16x32_f16(A[1][1], B1, acc1, 0, 0, 0);
        acc1 = __builtin_amdgcn_mfma_f32_16x16x32_f16(A[1][2], B2, acc1, 0, 0, 0);
        acc1 = __builtin_amdgcn_mfma_f32_16x16x32_f16(A[1][3], B3, acc1, 0, 0, 0);
        acc2 = __builtin_amdgcn_mfma_f32_16x16x32_f16(A[2][0], B0, acc2, 0, 0, 0);
        acc2 = __builtin_amdgcn_mfma_f32_16x16x32_f16(A[2][1], B1, acc2, 0, 0, 0);
        acc2 = __builtin_amdgcn_mfma_f32_16x16x32_f16(A[2][2], B2, acc2, 0, 0, 0);
        acc2 = __builtin_amdgcn_mfma_f32_16x16x32_f16(A[2][3], B3, acc2, 0, 0, 0);
        acc3 = __builtin_amdgcn_mfma_f32_16x16x32_f16(A[3][0], B0, acc3, 0, 0, 0);
        acc3 = __builtin_amdgcn_mfma_f32_16x16x32_f16(A[3][1], B1, acc3, 0, 0, 0);
        acc3 = __builtin_amdgcn_mfma_f32_16x16x32_f16(A[3][2], B2, acc3, 0, 0, 0);
        acc3 = __builtin_amdgcn_mfma_f32_16x16x32_f16(A[3][3], B3, acc3, 0, 0, 0);

        v4f g = mm == 0 ? acc0 : mm == 1 ? acc1 : mm == 2 ? acc2 : acc3;
        float gi = fsigmoid_(g[0]);
        float gf = fsigmoid_(g[1]);
        float gg = ftanh_(g[2]);
        float go = fsigmoid_(g[3]);
        c = gf * c + gi * gg;
        float hval = go * ftanh_(c);
        if (writer) {
            sh[(par ^ 1) * H_L + hu] = (half_t)hval;
            int n = n_begin + i;
            if (n >= write_start) hkeep[(size_t)(n - write_start) * H_L + hu] = hval;
        }
        BARRIER_LDS();
    }
    // hkeep is complete and lgkm-drained (final BARRIER_LDS) on return.
}

// final FC: 16 rows x 10 classes from hkeep
__device__ __forceinline__ void fc_out(const float* hkeep, const float* __restrict__ Wfc,
                                       const float* __restrict__ bfc, float* __restrict__ out,
                                       int blk) {
    int tid = threadIdx.x;
    if (tid < SEG_L * N_CLS) {
        int r = tid / N_CLS;
        int cc = tid - r * N_CLS;
        const float* wr = Wfc + (size_t)cc * H_L;
        float acc = bfc[cc];
        for (int k = 0; k < H_L; k += 4) {
            float4 hv = *(const float4*)&hkeep[r * H_L + k];
            float4 wv = *(const float4*)(wr + k);
            acc += hv.x * wv.x + hv.y * wv.y + hv.z * wv.z + hv.w * wv.w;
        }
        out[(size_t)(blk * SEG_L + r) * N_CLS + cc] = acc;
    }
}

// ---------------- the mega kernel ----------------
__global__ __launch_bounds__(512, 2) void k_mega(MegaArgs a) {
    __shared__ __align__(16) char smem[8704];   // max(sh+hkeep 8704, sA 8192, scan 2048, g64 4352)
    const int tid = threadIdx.x;
    const int blk = blockIdx.x;
    const int gi0 = blk * NTHR + tid;
    unsigned tgt = 0;
    float* sA = (float*)smem;

    // ---- S0: zero deg/cnt + weight prep + GCN gemm1 (all independent) ----
    if (gi0 < N_NODES) a.deg[gi0] = 0.0f;
    else if (gi0 < 2 * N_NODES) a.cnt[gi0 - N_NODES] = 0;
    for (int gi = gi0; gi < 262144; gi += TOTAL_THR) {
        if (gi < 131072) {
            int i = gi;
            int m = i >> 16;
            int r = i & 65535;
            int k = r >> 9;
            int j = r & 511;
            const float* A = m ? a.Wih2 : a.Wih1;
            a.WT[m * 65536 + k * 512 + j] = A[orig_col_(j) * 128 + k];
        } else {
            int i = gi - 131072;
            int L = i >> 16;
            int r = i & 65535;
            int j = r & 7;
            int lane = (r >> 3) & 63;
            int f = r >> 9;
            int kt = f & 3;
            int mt = (f >> 2) & 3;
            int w = f >> 4;
            int m = lane & 15, q = lane >> 4;
            int colp = w * 64 + mt * 16 + m;
            int oc = orig_col_(colp);
            int k = kt * 32 + q * 8 + j;
            const float* W = L ? a.Whh2 : a.Whh1;
            a.WhhF[i] = (half_t)W[(size_t)oc * 128 + k];
        }
    }
    gemm_g64(a.x11, a.W1, a.hw_buf, blk, sA);
    gsync(a.bar, tgt += NBLK);

    // ---- S1: degree atomics ----
    if (gi0 < N_EDGES) {
        int d = a.ecol[gi0];
        atomicAdd(&a.deg[d], a.ew[gi0]);
        atomicAdd(&a.cnt[d], 1);
    } else if (gi0 < N_EDGES + N_NODES) {
        int n = gi0 - N_EDGES;
        atomicAdd(&a.deg[n], 1.0f);
        atomicAdd(&a.cnt[n], 1);
    }
    gsync(a.bar, tgt += NBLK);

    // ---- S2: scan (block 0) + dinv (blocks 8..15) ----
    if (blk == 0) {
        scan512(a.cnt, a.row_ptr, (int*)smem);
    } else if (blk >= 8 && blk < 16) {
        int n = (blk - 8) * NTHR + tid;
        float d = a.deg[n];
        a.dinv[n] = d > 0.0f ? rsqrtf(d) : 0.0f;
    }
    gsync(a.bar, tgt += NBLK);

    // ---- S3: scatter into CSR ----
    if (gi0 < N_EDGES) {
        int d = a.ecol[gi0], sy = a.erow[gi0];
        int pos = atomicAdd(&a.cnt[d], 1);
        a.csr_src[pos] = sy;
        a.csr_w[pos] = a.dinv[sy] * a.ew[gi0] * a.dinv[d];
    } else if (gi0 < N_EDGES + N_NODES) {
        int n = gi0 - N_EDGES;
        int pos = atomicAdd(&a.cnt[n], 1);
        a.csr_src[pos] = n;
        float dv = a.dinv[n];
        a.csr_w[pos] = dv * dv;
    }
    gsync(a.bar, tgt += NBLK);

    // ---- S4: agg1 -> LDS -> gemm2 -> h_buf ----
    agg_lds(a.hw_buf, a.row_ptr, a.csr_src, a.csr_w, a.b1, sA, blk);
    __syncthreads();
    gemm_lds128(sA, a.W2, a.h_buf, blk);
    gsync(a.bar, tgt += NBLK);

    // ---- S5: agg2 -> LDS -> gemm3 -> hw_buf ----
    agg_lds(a.h_buf, a.row_ptr, a.csr_src, a.csr_w, a.b2, sA, blk);
    __syncthreads();
    gemm_lds128(sA, a.W3, a.hw_buf, blk);
    gsync(a.bar, tgt += NBLK);

    // ---- S6: agg3 -> LDS -> gemm_p1 -> P1 ----
    agg_lds(a.hw_buf, a.row_ptr, a.csr_src, a.csr_w, a.b3, sA, blk);
    __syncthreads();
    gemmp_lds(sA, a.WT, a.bih1, a.bhh1, a.P1, blk);
    gsync(a.bar, tgt += NBLK);

    // ---- S7: rec layer1 -> hkeep(LDS); gemm_p2 from hkeep -> P2 ----
    rec_seg(a.P1, a.WhhF, smem, blk);
    gemmp_lds((const float*)(smem + 512), a.WT + 65536, a.bih2, a.bhh2, a.P2, blk);
    gsync(a.bar, tgt += NBLK);

    // ---- S8: rec layer2 -> hkeep(LDS); FC -> out ----
    rec_seg(a.P2, a.WhhF + 65536, smem, blk);
    fc_out((const float*)(smem + 512), a.Wfc, a.bfc, a.out, blk);
}

extern "C" void kernel_launch(void* const* d_in, const int* in_sizes, int n_in,
                              void* d_out, int out_size, void* d_ws, size_t ws_size,
                              hipStream_t stream) {
    const float* x = (const float*)d_in[0];
    const int* eidx = (const int*)d_in[1];

    char* p = (char*)d_ws;
    auto alloc = [&](size_t bytes) -> char* {
        char* r = p;
        p += (bytes + 255) & ~(size_t)255;
        return r;
    };
    float* deg = (float*)alloc(N_NODES * 4);
    int* cnt = (int*)alloc(N_NODES * 4);
    float* dinv = (float*)alloc(N_NODES * 4);
    int* row_ptr = (int*)alloc((N_NODES + 1) * 4);
    int* csr_src = (int*)alloc((N_EDGES + N_NODES) * 4);
    float* csr_w = (float*)alloc((N_EDGES + N_NODES) * 4);
    float* WT = (float*)alloc(2 * 65536 * 4);
    half_t* WhhF = (half_t*)alloc(2 * 65536 * 2);
    float* h_buf = (float*)alloc((size_t)N_NODES * H_G * 4);
    float* hw_buf = (float*)alloc((size_t)N_NODES * H_G * 4);
    float* P1_buf = (float*)alloc((size_t)N_NODES * G4 * 4);
    float* P2_buf = (float*)alloc((size_t)N_NODES * G4 * 4);
    unsigned* bar = (unsigned*)alloc(256);

    MegaArgs args;
    args.x11 = x + (size_t)(T_STEPS - 1) * N_NODES * F_INP;
    args.erow = eidx;
    args.ecol = eidx + N_EDGES;
    args.ew = (const float*)d_in[2];
    args.W1 = (const float*)d_in[3];
    args.b1 = (const float*)d_in[4];
    args.W2 = (const float*)d_in[5];
    args.b2 = (const float*)d_in[6];
    args.W3 = (const float*)d_in[7];
    args.b3 = (const float*)d_in[8];
    args.Wih1 = (const float*)d_in[9];
    args.Whh1 = (const float*)d_in[10];
    args.bih1 = (const float*)d_in[11];
    args.bhh1 = (const float*)d_in[12];
    args.Wih2 = (const float*)d_in[13];
    args.Whh2 = (const float*)d_in[14];
    args.bih2 = (const float*)d_in[15];
    args.bhh2 = (const float*)d_in[16];
    args.Wfc = (const float*)d_in[17];
    args.bfc = (const float*)d_in[18];
    args.out = (float*)d_out;
    args.deg = deg;
    args.cnt = cnt;
    args.dinv = dinv;
    args.row_ptr = row_ptr;
    args.csr_src = csr_src;
    args.csr_w = csr_w;
    args.WT = WT;
    args.WhhF = WhhF;
    args.h_buf = h_buf;
    args.hw_buf = hw_buf;
    args.P1 = P1_buf;
    args.P2 = P2_buf;
    args.bar = bar;

    // barrier counter must be 0 at kernel start (workspace is poisoned between
    // iterations; this memset is captured in the graph and replayed each time)
    hipMemsetAsync(bar, 0, 64, stream);
    k_mega<<<NBLK, NTHR, 0, stream>>>(args);
}

// Round 3
// 373.746 us; speedup vs baseline: 1.2231x; 1.2231x over previous
//
#include <hip/hip_runtime.h>
#include <cstdint>
#include <cstddef>

// Problem constants
#define T_STEPS 12
#define N_NODES 4096
#define F_INP   64
#define H_G     128
#define H_L     128
#define N_CLS   10
#define N_EDGES 65536
#define G4      (4 * H_L)        // 512 gate columns

// Parallel-segment scan (verified in prior session: W=48 err <= 1.6e-7,
// 10x under the 1.76e-6 budget). Segments with s*L < W clamp to node 0 (EXACT).
#define SEG_L   16
#define SEG_W   48
#define NSEG    (N_NODES / SEG_L)   // 256 parallel segments

// R17: persistent mega-kernel, ACQUIRE-per-poll barrier -> 400us (per-poll
//      buffer_inv sc1 kept every XCD L2 permanently cold; FETCH 61MB).
// R18: relaxed-poll barrier + single release/acquire fences -> container
//      failed (cause unknown: infra flake, or relaxed agent loads served
//      stale from non-coherent XCD L2 -> unbounded-ish spin across bench
//      iterations).
// R19: same barrier as R18, hang-proofed:
//      (a) rare ACQUIRE fallback poll every 1024 relaxed polls -- if relaxed
//          loads are ever stale, acquire's invalidate forces observation;
//          costs <=1/1024 of R17's invalidation rate when healthy;
//      (b) tight guard (2^17 polls ~ 50ms/barrier) -> any pathology fails
//          visibly in seconds instead of killing the container.

#define NBLK    256
#define NTHR    512
#define TOTAL_THR (NBLK * NTHR)     // 131072

typedef _Float16 half_t;
typedef half_t v8h __attribute__((ext_vector_type(8)));
typedef float v4f __attribute__((ext_vector_type(4)));

// Raw barrier: LDS-only drain (prior-session win). __syncthreads() would drain
// vmcnt(0) every step, stalling the in-flight P prefetch.
#define BARRIER_LDS() asm volatile("s_waitcnt lgkmcnt(0)\n\ts_barrier" ::: "memory")

// Keepalive pin: forces fragment liveness; harmless either way.
#define PIN_V(x) asm volatile("" : "+v"(x))

// fast sigmoid/tanh: v_exp_f32 + v_rcp_f32 only
__device__ __forceinline__ float fsigmoid_(float x) {
    float e = __builtin_amdgcn_exp2f(-1.44269504f * x);
    return __builtin_amdgcn_rcpf(1.0f + e);
}
__device__ __forceinline__ float ftanh_(float x) {
    float e = __builtin_amdgcn_exp2f(2.88539008f * x);
    return 1.0f - 2.0f * __builtin_amdgcn_rcpf(e + 1.0f);
}
__device__ __forceinline__ float geluf_(float x) { return 0.5f * x * (1.0f + erff(x * 0.70710678f)); }

// gate-column permutation: col' = 4*hu + gate  ->  natural col = gate*128 + hu
__device__ __forceinline__ int orig_col_(int cp) { return (cp & 3) * 128 + (cp >> 2); }

// ---------------- grid barrier (agent scope, phase-counting) ----------------
// bar is memset to 0 before each launch. Barrier k waits for count 256*(k+1).
// RELEASE fence (L2 wb) once -> RELAXED add -> RELAXED spin (agent-scope
// relaxed atomic loads carry sc1 on gfx940+, i.e. read past the non-coherent
// XCD L2) -> rare ACQUIRE fallback poll -> ACQUIRE fence once after exit.
// One wb + one inv per block per barrier == what a kernel boundary costs,
// minus the launch. Bounded spin: fail visibly, never hang.
__device__ __forceinline__ void gsync(unsigned* bar, unsigned target) {
    __syncthreads();   // block-local order + lgkm/vm drain per wave
    if (threadIdx.x == 0) {
        __builtin_amdgcn_fence(__ATOMIC_RELEASE, "agent");
        __hip_atomic_fetch_add(bar, 1u, __ATOMIC_RELAXED, __HIP_MEMORY_SCOPE_AGENT);
        int guard = 0;
        for (;;) {
            unsigned v = __hip_atomic_load(bar, __ATOMIC_RELAXED, __HIP_MEMORY_SCOPE_AGENT);
            if (v >= target) break;
            if ((++guard & 1023) == 0) {
                // fallback: acquire poll (forces L1/L2 inv -> fresh read) in
                // case relaxed agent loads are ever served stale
                v = __hip_atomic_load(bar, __ATOMIC_ACQUIRE, __HIP_MEMORY_SCOPE_AGENT);
                if (v >= target) break;
                if (guard > (1 << 17)) break;   // ~50ms cap: fail visibly
            }
            __builtin_amdgcn_s_sleep(8);
        }
        __builtin_amdgcn_fence(__ATOMIC_ACQUIRE, "agent");
    }
    __syncthreads();
}

// ---------------- kernel argument block ----------------
struct MegaArgs {
    const float* x11;
    const int* erow;
    const int* ecol;
    const float* ew;
    const float *W1, *b1, *W2, *b2, *W3, *b3;
    const float *Wih1, *Wih2, *Whh1, *Whh2;
    const float *bih1, *bhh1, *bih2, *bhh2;
    const float *Wfc, *bfc;
    float* out;
    float* deg;
    int* cnt;
    float* dinv;
    int* row_ptr;
    int* csr_src;
    float* csr_w;
    float* WT;          // WihT1_perm | WihT2_perm (2 x 65536 floats)
    half_t* WhhF;       // f16 fragment weights, both layers (2 x 65536 halfs)
    float* h_buf;       // GCN ping
    float* hw_buf;      // GCN pong
    float* P1;
    float* P2;
    unsigned* bar;
};

// ---------------- stage device functions (all force-inlined) ----------------

// exclusive scan of cnt[4096] -> row_ptr + cursor(cnt); block 0 only, 512 thr
__device__ __forceinline__ void scan512(int* cnt, int* row_ptr, int* s) {
    int tid = threadIdx.x;
    int4 va = ((const int4*)cnt)[tid * 2];
    int4 vb = ((const int4*)cnt)[tid * 2 + 1];
    int local = va.x + va.y + va.z + va.w + vb.x + vb.y + vb.z + vb.w;
    s[tid] = local;
    __syncthreads();
    for (int off = 1; off < 512; off <<= 1) {
        int v = (tid >= off) ? s[tid - off] : 0;
        __syncthreads();
        s[tid] += v;
        __syncthreads();
    }
    int base = s[tid] - local;
    int4 oa, ob;
    oa.x = base;
    oa.y = oa.x + va.x;
    oa.z = oa.y + va.y;
    oa.w = oa.z + va.z;
    ob.x = oa.w + va.w;
    ob.y = ob.x + vb.x;
    ob.z = ob.y + vb.y;
    ob.w = ob.z + vb.z;
    ((int4*)row_ptr)[tid * 2] = oa;
    ((int4*)row_ptr)[tid * 2 + 1] = ob;
    ((int4*)cnt)[tid * 2] = oa;          // cursor for scatter
    ((int4*)cnt)[tid * 2 + 1] = ob;
    if (tid == 511) row_ptr[4096] = ob.w + vb.w;
}

// C[16,128] = A[16rows from global, K] @ B[K,128], K=64 (GCN layer 1)
__device__ __forceinline__ void gemm_g64(const float* __restrict__ A,
                                         const float* __restrict__ B,
                                         float* __restrict__ C, int blk, float* sA) {
    constexpr int K = F_INP, KP = K + 4;
    int tid = threadIdx.x;
    size_t m0 = (size_t)blk * 16;
    for (int task = tid; task < 16 * (K / 4); task += NTHR) {
        int rr = task >> 4, kc = task & 15;
        *(float4*)&sA[rr * KP + kc * 4] = *(const float4*)(A + (m0 + rr) * K + kc * 4);
    }
    __syncthreads();
    int tn = tid & 31;
    int tm = tid >> 5;   // 16 rows, 1 row/thread
    float a0 = 0.f, a1 = 0.f, a2 = 0.f, a3 = 0.f;
    for (int k = 0; k < K; k += 4) {
        float4 b0 = *(const float4*)(B + (size_t)(k + 0) * H_G + tn * 4);
        float4 b1 = *(const float4*)(B + (size_t)(k + 1) * H_G + tn * 4);
        float4 b2 = *(const float4*)(B + (size_t)(k + 2) * H_G + tn * 4);
        float4 b3 = *(const float4*)(B + (size_t)(k + 3) * H_G + tn * 4);
        float4 aa = *(const float4*)&sA[tm * KP + k];
        a0 += aa.x * b0.x + aa.y * b1.x + aa.z * b2.x + aa.w * b3.x;
        a1 += aa.x * b0.y + aa.y * b1.y + aa.z * b2.y + aa.w * b3.y;
        a2 += aa.x * b0.z + aa.y * b1.z + aa.z * b2.z + aa.w * b3.z;
        a3 += aa.x * b0.w + aa.y * b1.w + aa.z * b2.w + aa.w * b3.w;
    }
    *(float4*)(C + (m0 + tm) * H_G + tn * 4) = make_float4(a0, a1, a2, a3);
}

// CSR aggregation + bias + exact GELU for this block's 16 nodes -> LDS sA[16][128]
__device__ __forceinline__ void agg_lds(const float* __restrict__ hw,
                                        const int* __restrict__ row_ptr,
                                        const int* __restrict__ csr_src,
                                        const float* __restrict__ csr_w,
                                        const float* __restrict__ bias,
                                        float* sA, int blk) {
    int tid = threadIdx.x;
    int f4 = tid & 31;
    int nsub = tid >> 5;            // 16 nodes/block
    int n = blk * 16 + nsub;
    float4 acc = make_float4(0.f, 0.f, 0.f, 0.f);
    int e0 = row_ptr[n], e1 = row_ptr[n + 1];
    for (int e = e0; e < e1; e++) {
        int s = csr_src[e];
        float wv = csr_w[e];
        float4 v = *(const float4*)(hw + (size_t)s * H_G + f4 * 4);
        acc.x += wv * v.x;
        acc.y += wv * v.y;
        acc.z += wv * v.z;
        acc.w += wv * v.w;
    }
    float4 b = *(const float4*)(bias + f4 * 4);
    float4 o;
    o.x = geluf_(acc.x + b.x);
    o.y = geluf_(acc.y + b.y);
    o.z = geluf_(acc.z + b.z);
    o.w = geluf_(acc.w + b.w);
    *(float4*)&sA[nsub * 128 + f4 * 4] = o;
}

// C[16,128] = sA[16,128](LDS) @ B[128,128] (GCN layers 2/3)
__device__ __forceinline__ void gemm_lds128(const float* sA,
                                            const float* __restrict__ B,
                                            float* __restrict__ C, int blk) {
    int tid = threadIdx.x;
    size_t m0 = (size_t)blk * 16;
    int tn = tid & 31;
    int tm = tid >> 5;
    float a0 = 0.f, a1 = 0.f, a2 = 0.f, a3 = 0.f;
    for (int k = 0; k < H_G; k += 4) {
        float4 b0 = *(const float4*)(B + (size_t)(k + 0) * H_G + tn * 4);
        float4 b1 = *(const float4*)(B + (size_t)(k + 1) * H_G + tn * 4);
        float4 b2 = *(const float4*)(B + (size_t)(k + 2) * H_G + tn * 4);
        float4 b3 = *(const float4*)(B + (size_t)(k + 3) * H_G + tn * 4);
        float4 aa = *(const float4*)&sA[tm * 128 + k];
        a0 += aa.x * b0.x + aa.y * b1.x + aa.z * b2.x + aa.w * b3.x;
        a1 += aa.x * b0.y + aa.y * b1.y + aa.z * b2.y + aa.w * b3.y;
        a2 += aa.x * b0.z + aa.y * b1.z + aa.z * b2.z + aa.w * b3.z;
        a3 += aa.x * b0.w + aa.y * b1.w + aa.z * b2.w + aa.w * b3.w;
    }
    *(float4*)(C + (m0 + tm) * H_G + tn * 4) = make_float4(a0, a1, a2, a3);
}

// P[16 rows, 512] = Arows(LDS 16x128) @ BT[128,512] + permuted bias
__device__ __forceinline__ void gemmp_lds(const float* sArows,
                                          const float* __restrict__ BT,
                                          const float* __restrict__ bih,
                                          const float* __restrict__ bhh,
                                          float* __restrict__ Pout, int blk) {
    int tid = threadIdx.x;
    int r0 = blk * 16;
    int jc = tid & 127;
    int rg = tid >> 7;   // 4 groups x 4 rows
    float acc[4][4];
#pragma unroll
    for (int rr = 0; rr < 4; rr++)
#pragma unroll
        for (int j = 0; j < 4; j++) acc[rr][j] = 0.f;

    for (int k = 0; k < 128; k += 4) {
        float4 b0 = *(const float4*)(BT + (size_t)(k + 0) * G4 + jc * 4);
        float4 b1 = *(const float4*)(BT + (size_t)(k + 1) * G4 + jc * 4);
        float4 b2 = *(const float4*)(BT + (size_t)(k + 2) * G4 + jc * 4);
        float4 b3 = *(const float4*)(BT + (size_t)(k + 3) * G4 + jc * 4);
#pragma unroll
        for (int rr = 0; rr < 4; rr++) {
            float4 a = *(const float4*)&sArows[(rg * 4 + rr) * 128 + k];
            acc[rr][0] += a.x * b0.x + a.y * b1.x + a.z * b2.x + a.w * b3.x;
            acc[rr][1] += a.x * b0.y + a.y * b1.y + a.z * b2.y + a.w * b3.y;
            acc[rr][2] += a.x * b0.z + a.y * b1.z + a.z * b2.z + a.w * b3.z;
            acc[rr][3] += a.x * b0.w + a.y * b1.w + a.z * b2.w + a.w * b3.w;
        }
    }
    int c0 = jc * 4;
    float bx = bih[orig_col_(c0 + 0)] + bhh[orig_col_(c0 + 0)];
    float by = bih[orig_col_(c0 + 1)] + bhh[orig_col_(c0 + 1)];
    float bz = bih[orig_col_(c0 + 2)] + bhh[orig_col_(c0 + 2)];
    float bw = bih[orig_col_(c0 + 3)] + bhh[orig_col_(c0 + 3)];
#pragma unroll
    for (int rr = 0; rr < 4; rr++) {
        int lrow = r0 + rg * 4 + rr;
        *(float4*)(Pout + (size_t)lrow * G4 + jc * 4) =
            make_float4(acc[rr][0] + bx, acc[rr][1] + by, acc[rr][2] + bz, acc[rr][3] + bw);
    }
}

// MFMA LSTM recurrence for segment s; kept h rows land in LDS hkeep (smem+512)
__device__ __forceinline__ void rec_seg(const float* __restrict__ P,
                                        const half_t* __restrict__ WhhF,
                                        char* smem, int s) {
    half_t* sh = (half_t*)smem;              // [2][128] ping-pong h (f16)
    float* hkeep = (float*)(smem + 512);     // [16][128] kept h rows (f32)
    int write_start = s * SEG_L;
    int n_begin = write_start - SEG_W;
    if (n_begin < 0) n_begin = 0;
    int steps = write_start + SEG_L - n_begin;
    const float* Pp = P + (size_t)n_begin * G4;

    int tid = threadIdx.x;
    int lane = tid & 63;
    int w = tid >> 6;
    int m = lane & 15;
    int q = lane >> 4;
    int mm = m & 3;
    int hu = w * 16 + mm * 4 + q;

    const v8h* Af = (const v8h*)WhhF + (size_t)w * 16 * 64 + lane;
    v8h A[4][4];
#pragma unroll
    for (int mt = 0; mt < 4; mt++)
#pragma unroll
        for (int kt = 0; kt < 4; kt++)
            A[mt][kt] = Af[(mt * 4 + kt) * 64];
#pragma unroll
    for (int mt = 0; mt < 4; mt++)
#pragma unroll
        for (int kt = 0; kt < 4; kt++)
            PIN_V(A[mt][kt]);

    float c = 0.f;
    if (tid < H_L) sh[tid] = (half_t)0.f;

    v4f pn[2][4];
    const float* pb0 = Pp + w * 64 + q * 4;
#pragma unroll
    for (int s2 = 0; s2 < 2; s2++)
#pragma unroll
        for (int mt = 0; mt < 4; mt++)
            pn[s2][mt] = *(const v4f*)(pb0 + (size_t)s2 * G4 + mt * 16);
    __syncthreads();

    bool writer = (m < 4);

#pragma unroll 2
    for (int i = 0; i < steps; i++) {
        int par = i & 1;
        v4f acc0 = pn[par][0], acc1 = pn[par][1], acc2 = pn[par][2], acc3 = pn[par][3];
        int inx = (i + 2 < steps) ? (i + 2) : i;
        const float* pb = Pp + (size_t)inx * G4 + w * 64 + q * 4;
        pn[par][0] = *(const v4f*)(pb + 0);
        pn[par][1] = *(const v4f*)(pb + 16);
        pn[par][2] = *(const v4f*)(pb + 32);
        pn[par][3] = *(const v4f*)(pb + 48);

        const half_t* shc = sh + par * H_L;
        v8h B0 = *(const v8h*)(shc + q * 8);
        v8h B1 = *(const v8h*)(shc + 32 + q * 8);
        v8h B2 = *(const v8h*)(shc + 64 + q * 8);
        v8h B3 = *(const v8h*)(shc + 96 + q * 8);

        acc0 = __builtin_amdgcn_mfma_f32_16x16x32_f16(A[0][0], B0, acc0, 0, 0, 0);
        acc0 = __builtin_amdgcn_mfma_f32_16x16x32_f16(A[0][1], B1, acc0, 0, 0, 0);
        acc0 = __builtin_amdgcn_mfma_f32_16x16x32_f16(A[0][2], B2, acc0, 0, 0, 0);
        acc0 = __builtin_amdgcn_mfma_f32_16x16x32_f16(A[0][3], B3, acc0, 0, 0, 0);
        acc1 = __builtin_amdgcn_mfma_f32_16x16x32_f16(A[1][0], B0, acc1, 0, 0, 0);
        acc1 = __builtin_amdgcn_mfma_f32_16x16x32_f16(A[1][1], B1, acc1, 0, 0, 0);
        acc1 = __builtin_amdgcn_mfma_f32_16x16x32_f16(A[1][2], B2, acc1, 0, 0, 0);
        acc1 = __builtin_amdgcn_mfma_f32_16x16x32_f16(A[1][3], B3, acc1, 0, 0, 0);
        acc2 = __builtin_amdgcn_mfma_f32_16x16x32_f16(A[2][0], B0, acc2, 0, 0, 0);
        acc2 = __builtin_amdgcn_mfma_f32_16x16x32_f16(A[2][1], B1, acc2, 0, 0, 0);
        acc2 = __builtin_amdgcn_mfma_f32_16x16x32_f16(A[2][2], B2, acc2, 0, 0, 0);
        acc2 = __builtin_amdgcn_mfma_f32_16x16x32_f16(A[2][3], B3, acc2, 0, 0, 0);
        acc3 = __builtin_amdgcn_mfma_f32_16x16x32_f16(A[3][0], B0, acc3, 0, 0, 0);
        acc3 = __builtin_amdgcn_mfma_f32_16x16x32_f16(A[3][1], B1, acc3, 0, 0, 0);
        acc3 = __builtin_amdgcn_mfma_f32_16x16x32_f16(A[3][2], B2, acc3, 0, 0, 0);
        acc3 = __builtin_amdgcn_mfma_f32_16x16x32_f16(A[3][3], B3, acc3, 0, 0, 0);

        v4f g = mm == 0 ? acc0 : mm == 1 ? acc1 : mm == 2 ? acc2 : acc3;
        float gi = fsigmoid_(g[0]);
        float gf = fsigmoid_(g[1]);
        float gg = ftanh_(g[2]);
        float go = fsigmoid_(g[3]);
        c = gf * c + gi * gg;
        float hval = go * ftanh_(c);
        if (writer) {
            sh[(par ^ 1) * H_L + hu] = (half_t)hval;
            int n = n_begin + i;
            if (n >= write_start) hkeep[(size_t)(n - write_start) * H_L + hu] = hval;
        }
        BARRIER_LDS();
    }
    // hkeep is complete and lgkm-drained (final BARRIER_LDS) on return.
}

// final FC: 16 rows x 10 classes from hkeep
__device__ __forceinline__ void fc_out(const float* hkeep, const float* __restrict__ Wfc,
                                       const float* __restrict__ bfc, float* __restrict__ out,
                                       int blk) {
    int tid = threadIdx.x;
    if (tid < SEG_L * N_CLS) {
        int r = tid / N_CLS;
        int cc = tid - r * N_CLS;
        const float* wr = Wfc + (size_t)cc * H_L;
        float acc = bfc[cc];
        for (int k = 0; k < H_L; k += 4) {
            float4 hv = *(const float4*)&hkeep[r * H_L + k];
            float4 wv = *(const float4*)(wr + k);
            acc += hv.x * wv.x + hv.y * wv.y + hv.z * wv.z + hv.w * wv.w;
        }
        out[(size_t)(blk * SEG_L + r) * N_CLS + cc] = acc;
    }
}

// ---------------- the mega kernel ----------------
__global__ __launch_bounds__(512, 2) void k_mega(MegaArgs a) {
    __shared__ __align__(16) char smem[8704];   // max(sh+hkeep 8704, sA 8192, scan 2048, g64 4352)
    const int tid = threadIdx.x;
    const int blk = blockIdx.x;
    const int gi0 = blk * NTHR + tid;
    unsigned tgt = 0;
    float* sA = (float*)smem;

    // ---- S0: zero deg/cnt + weight prep + GCN gemm1 (all independent) ----
    if (gi0 < N_NODES) a.deg[gi0] = 0.0f;
    else if (gi0 < 2 * N_NODES) a.cnt[gi0 - N_NODES] = 0;
    for (int gi = gi0; gi < 262144; gi += TOTAL_THR) {
        if (gi < 131072) {
            int i = gi;
            int m = i >> 16;
            int r = i & 65535;
            int k = r >> 9;
            int j = r & 511;
            const float* A = m ? a.Wih2 : a.Wih1;
            a.WT[m * 65536 + k * 512 + j] = A[orig_col_(j) * 128 + k];
        } else {
            int i = gi - 131072;
            int L = i >> 16;
            int r = i & 65535;
            int j = r & 7;
            int lane = (r >> 3) & 63;
            int f = r >> 9;
            int kt = f & 3;
            int mt = (f >> 2) & 3;
            int w = f >> 4;
            int m = lane & 15, q = lane >> 4;
            int colp = w * 64 + mt * 16 + m;
            int oc = orig_col_(colp);
            int k = kt * 32 + q * 8 + j;
            const float* W = L ? a.Whh2 : a.Whh1;
            a.WhhF[i] = (half_t)W[(size_t)oc * 128 + k];
        }
    }
    gemm_g64(a.x11, a.W1, a.hw_buf, blk, sA);
    gsync(a.bar, tgt += NBLK);

    // ---- S1: degree atomics ----
    if (gi0 < N_EDGES) {
        int d = a.ecol[gi0];
        atomicAdd(&a.deg[d], a.ew[gi0]);
        atomicAdd(&a.cnt[d], 1);
    } else if (gi0 < N_EDGES + N_NODES) {
        int n = gi0 - N_EDGES;
        atomicAdd(&a.deg[n], 1.0f);
        atomicAdd(&a.cnt[n], 1);
    }
    gsync(a.bar, tgt += NBLK);

    // ---- S2: scan (block 0) + dinv (blocks 8..15) ----
    if (blk == 0) {
        scan512(a.cnt, a.row_ptr, (int*)smem);
    } else if (blk >= 8 && blk < 16) {
        int n = (blk - 8) * NTHR + tid;
        float d = a.deg[n];
        a.dinv[n] = d > 0.0f ? rsqrtf(d) : 0.0f;
    }
    gsync(a.bar, tgt += NBLK);

    // ---- S3: scatter into CSR ----
    if (gi0 < N_EDGES) {
        int d = a.ecol[gi0], sy = a.erow[gi0];
        int pos = atomicAdd(&a.cnt[d], 1);
        a.csr_src[pos] = sy;
        a.csr_w[pos] = a.dinv[sy] * a.ew[gi0] * a.dinv[d];
    } else if (gi0 < N_EDGES + N_NODES) {
        int n = gi0 - N_EDGES;
        int pos = atomicAdd(&a.cnt[n], 1);
        a.csr_src[pos] = n;
        float dv = a.dinv[n];
        a.csr_w[pos] = dv * dv;
    }
    gsync(a.bar, tgt += NBLK);

    // ---- S4: agg1 -> LDS -> gemm2 -> h_buf ----
    agg_lds(a.hw_buf, a.row_ptr, a.csr_src, a.csr_w, a.b1, sA, blk);
    __syncthreads();
    gemm_lds128(sA, a.W2, a.h_buf, blk);
    gsync(a.bar, tgt += NBLK);

    // ---- S5: agg2 -> LDS -> gemm3 -> hw_buf ----
    agg_lds(a.h_buf, a.row_ptr, a.csr_src, a.csr_w, a.b2, sA, blk);
    __syncthreads();
    gemm_lds128(sA, a.W3, a.hw_buf, blk);
    gsync(a.bar, tgt += NBLK);

    // ---- S6: agg3 -> LDS -> gemm_p1 -> P1 ----
    agg_lds(a.hw_buf, a.row_ptr, a.csr_src, a.csr_w, a.b3, sA, blk);
    __syncthreads();
    gemmp_lds(sA, a.WT, a.bih1, a.bhh1, a.P1, blk);
    gsync(a.bar, tgt += NBLK);

    // ---- S7: rec layer1 -> hkeep(LDS); gemm_p2 from hkeep -> P2 ----
    rec_seg(a.P1, a.WhhF, smem, blk);
    gemmp_lds((const float*)(smem + 512), a.WT + 65536, a.bih2, a.bhh2, a.P2, blk);
    gsync(a.bar, tgt += NBLK);

    // ---- S8: rec layer2 -> hkeep(LDS); FC -> out ----
    rec_seg(a.P2, a.WhhF + 65536, smem, blk);
    fc_out((const float*)(smem + 512), a.Wfc, a.bfc, a.out, blk);
}

extern "C" void kernel_launch(void* const* d_in, const int* in_sizes, int n_in,
                              void* d_out, int out_size, void* d_ws, size_t ws_size,
                              hipStream_t stream) {
    const float* x = (const float*)d_in[0];
    const int* eidx = (const int*)d_in[1];

    char* p = (char*)d_ws;
    auto alloc = [&](size_t bytes) -> char* {
        char* r = p;
        p += (bytes + 255) & ~(size_t)255;
        return r;
    };
    float* deg = (float*)alloc(N_NODES * 4);
    int* cnt = (int*)alloc(N_NODES * 4);
    float* dinv = (float*)alloc(N_NODES * 4);
    int* row_ptr = (int*)alloc((N_NODES + 1) * 4);
    int* csr_src = (int*)alloc((N_EDGES + N_NODES) * 4);
    float* csr_w = (float*)alloc((N_EDGES + N_NODES) * 4);
    float* WT = (float*)alloc(2 * 65536 * 4);
    half_t* WhhF = (half_t*)alloc(2 * 65536 * 2);
    float* h_buf = (float*)alloc((size_t)N_NODES * H_G * 4);
    float* hw_buf = (float*)alloc((size_t)N_NODES * H_G * 4);
    float* P1_buf = (float*)alloc((size_t)N_NODES * G4 * 4);
    float* P2_buf = (float*)alloc((size_t)N_NODES * G4 * 4);
    unsigned* bar = (unsigned*)alloc(256);

    MegaArgs args;
    args.x11 = x + (size_t)(T_STEPS - 1) * N_NODES * F_INP;
    args.erow = eidx;
    args.ecol = eidx + N_EDGES;
    args.ew = (const float*)d_in[2];
    args.W1 = (const float*)d_in[3];
    args.b1 = (const float*)d_in[4];
    args.W2 = (const float*)d_in[5];
    args.b2 = (const float*)d_in[6];
    args.W3 = (const float*)d_in[7];
    args.b3 = (const float*)d_in[8];
    args.Wih1 = (const float*)d_in[9];
    args.Whh1 = (const float*)d_in[10];
    args.bih1 = (const float*)d_in[11];
    args.bhh1 = (const float*)d_in[12];
    args.Wih2 = (const float*)d_in[13];
    args.Whh2 = (const float*)d_in[14];
    args.bih2 = (const float*)d_in[15];
    args.bhh2 = (const float*)d_in[16];
    args.Wfc = (const float*)d_in[17];
    args.bfc = (const float*)d_in[18];
    args.out = (float*)d_out;
    args.deg = deg;
    args.cnt = cnt;
    args.dinv = dinv;
    args.row_ptr = row_ptr;
    args.csr_src = csr_src;
    args.csr_w = csr_w;
    args.WT = WT;
    args.WhhF = WhhF;
    args.h_buf = h_buf;
    args.hw_buf = hw_buf;
    args.P1 = P1_buf;
    args.P2 = P2_buf;
    args.bar = bar;

    // barrier counter must be 0 at kernel start (workspace is poisoned between
    // iterations; this memset is captured in the graph and replayed each time)
    hipMemsetAsync(bar, 0, 64, stream);
    k_mega<<<NBLK, NTHR, 0, stream>>>(args);
}